// Round 1
// baseline (677.301 us; speedup 1.0000x reference)
//
#include <hip/hip_runtime.h>
#include <math.h>

// FlowMatching: out = t * gaussian_blur(x, sigma(t)) + (1-t) * x
// x: (128, 3, 512, 512) fp32, t: (128,) fp32
// sigma = 0.1 + 0.9*t ; K=9 taps (R=4), per-batch kernel, zero padding.
// Gaussian kernel is separable (masked outer product, normalization
// factorizes), so we do two 1D 9-tap passes fused in one kernel.

#define TILE 64
#define HALO 4
#define KK 9
#define LW 72           // TILE + 2*HALO
#define IMG 512

__global__ __launch_bounds__(256) void blur_blend_kernel(
    const float* __restrict__ x, const float* __restrict__ t,
    float* __restrict__ out)
{
    // 39168 B LDS -> 4 blocks/CU
    __shared__ __align__(16) float s_in[LW][LW];    // 72x72 input tile + halo
    __shared__ __align__(16) float s_tmp[LW][TILE]; // horizontal-pass result

    const int tid   = threadIdx.x;        // 0..255
    const int bx    = blockIdx.x;         // tile col 0..7
    const int by    = blockIdx.y;         // tile row 0..7
    const int plane = blockIdx.z;         // 0..383  (b*3 + c)
    const int b     = plane / 3;

    // ---- per-batch 1D weights (uniform across block; computed redundantly)
    const float tb     = t[b];
    const float sigma  = 0.1f + tb * 0.9f;
    const float r      = ceilf(4.0f * sigma);
    const float inv2s2 = 1.0f / (2.0f * sigma * sigma);
    float w[KK];
    float wsum = 0.0f;
#pragma unroll
    for (int k = 0; k < KK; ++k) {
        float d = (float)(k - HALO);
        float v = (fabsf(d) <= r) ? expf(-d * d * inv2s2) : 0.0f;
        w[k] = v;
        wsum += v;
    }
    const float winv = 1.0f / wsum;
#pragma unroll
    for (int k = 0; k < KK; ++k) w[k] *= winv;

    const float* plane_in  = x   + (size_t)plane * IMG * IMG;
    float*       plane_out = out + (size_t)plane * IMG * IMG;
    const int gx0 = bx * TILE - HALO;
    const int gy0 = by * TILE - HALO;

    // ---- stage 1: global -> LDS, 72x72 tile as float4 quads (18 quads/row)
    for (int slot = tid; slot < LW * (LW / 4); slot += 256) {
        const int row = slot / (LW / 4);
        const int qc  = slot % (LW / 4);
        const int gy  = gy0 + row;
        const int gx  = gx0 + qc * 4;
        float4 v = make_float4(0.f, 0.f, 0.f, 0.f);
        if ((unsigned)gy < (unsigned)IMG) {
            if (gx >= 0 && gx + 3 < IMG) {
                v = *(const float4*)(plane_in + (size_t)gy * IMG + gx);
            } else {
                float* pv = &v.x;
#pragma unroll
                for (int j = 0; j < 4; ++j) {
                    const int g = gx + j;
                    if ((unsigned)g < (unsigned)IMG)
                        pv[j] = plane_in[(size_t)gy * IMG + g];
                }
            }
        }
        *(float4*)&s_in[row][qc * 4] = v;
    }
    __syncthreads();

    // ---- stage 2: horizontal 9-tap pass over all 72 rows x 64 cols
    for (int slot = tid; slot < LW * (TILE / 4); slot += 256) {
        const int row = slot / (TILE / 4);
        const int qc  = slot % (TILE / 4);
        float f[12];
        *(float4*)&f[0] = *(const float4*)&s_in[row][qc * 4 + 0];
        *(float4*)&f[4] = *(const float4*)&s_in[row][qc * 4 + 4];
        *(float4*)&f[8] = *(const float4*)&s_in[row][qc * 4 + 8];
        float4 o;
        float* po = &o.x;
#pragma unroll
        for (int j = 0; j < 4; ++j) {
            float acc = 0.0f;
#pragma unroll
            for (int k = 0; k < KK; ++k) acc += w[k] * f[j + k];
            po[j] = acc;
        }
        *(float4*)&s_tmp[row][qc * 4] = o;
    }
    __syncthreads();

    // ---- stage 3: vertical 9-tap pass + blend + coalesced float4 store
    const float one_m_t = 1.0f - tb;
    for (int slot = tid; slot < TILE * (TILE / 4); slot += 256) {
        const int row = slot / (TILE / 4);   // 0..63
        const int qc  = slot % (TILE / 4);   // 0..15
        float4 acc = make_float4(0.f, 0.f, 0.f, 0.f);
#pragma unroll
        for (int k = 0; k < KK; ++k) {
            const float4 v = *(const float4*)&s_tmp[row + k][qc * 4];
            acc.x += w[k] * v.x;
            acc.y += w[k] * v.y;
            acc.z += w[k] * v.z;
            acc.w += w[k] * v.w;
        }
        const float4 orig = *(const float4*)&s_in[row + HALO][qc * 4 + HALO];
        float4 res;
        res.x = tb * acc.x + one_m_t * orig.x;
        res.y = tb * acc.y + one_m_t * orig.y;
        res.z = tb * acc.z + one_m_t * orig.z;
        res.w = tb * acc.w + one_m_t * orig.w;
        const int gy = by * TILE + row;
        const int gx = bx * TILE + qc * 4;
        *(float4*)(plane_out + (size_t)gy * IMG + gx) = res;
    }
}

extern "C" void kernel_launch(void* const* d_in, const int* in_sizes, int n_in,
                              void* d_out, int out_size, void* d_ws, size_t ws_size,
                              hipStream_t stream) {
    const float* x = (const float*)d_in[0];   // (128,3,512,512)
    const float* t = (const float*)d_in[1];   // (128,)
    float* out = (float*)d_out;
    dim3 grid(IMG / TILE, IMG / TILE, 128 * 3);  // (8, 8, 384)
    blur_blend_kernel<<<grid, 256, 0, stream>>>(x, t, out);
}